// Round 1
// baseline (322.060 us; speedup 1.0000x reference)
//
#include <hip/hip_runtime.h>
#include <stdint.h>

// Fused Swin window-attention, MI355X gfx950.
// One workgroup (512 thr = 8 waves) per window; wave w = head w.
// All GEMMs via v_mfma_f32_16x16x32_bf16. fp32 in/out, bf16 internal.

#define WN 49      // tokens per window
#define CD 256     // channels
#define NH 8       // heads

typedef float  f32x4  __attribute__((ext_vector_type(4)));
typedef short  bf16x8 __attribute__((ext_vector_type(8)));

#define MFMA16(a,b,c) __builtin_amdgcn_mfma_f32_16x16x32_bf16((a),(b),(c),0,0,0)

__device__ __forceinline__ unsigned short f2bf(float f) {
  union { float f; unsigned u; } c; c.f = f;
  unsigned x = c.u;
  x += 0x7FFFu + ((x >> 16) & 1u);          // round-to-nearest-even
  return (unsigned short)(x >> 16);
}
__device__ __forceinline__ unsigned pk2(float a, float b) {
  union { float f; unsigned u; } ca, cb; ca.f = a; cb.f = b;
  unsigned xx = ca.u, yy = cb.u;
  xx += 0x7FFFu + ((xx >> 16) & 1u);
  yy += 0x7FFFu + ((yy >> 16) & 1u);
  return (xx >> 16) | (yy & 0xFFFF0000u);
}

// ---------------- workspace layout (bytes) ----------------
// WQKV : [8 h][8 kk][6 fb][64 lane][8 bf16]  fragment-major qkv_w   = 393216
// WPROJ: [8 kk][16 fb][64 lane][8 bf16]      fragment-major proj_w  = 131072
// BIAS : [8 h][64 j][64 i] f32 (j>=49 -> -1e4)                      = 131072
// MASK : [64 w][64 j][64 i] f32 (padded with 0)                     = 1048576
#define WS_WQKV  0
#define WS_WPROJ 393216
#define WS_BIAS  524288
#define WS_MASK  655360

__global__ __launch_bounds__(256) void prep_kernel(
    const float* __restrict__ qkv_w, const float* __restrict__ proj_w,
    const float* __restrict__ rpb,   const int*   __restrict__ relidx,
    const float* __restrict__ mask,
    unsigned short* __restrict__ wqkv, unsigned short* __restrict__ wproj,
    float* __restrict__ biasm, float* __restrict__ maskp)
{
  int t = blockIdx.x * blockDim.x + threadIdx.x;
  if (t < 8*8*6*64) {                      // qkv_w fragments, head-grouped rows
    int l    = t & 63;
    int fb   = (t >> 6) % 6;
    int rest = t / (64*6);
    int kk = rest & 7, h = rest >> 3;
    int rbase = (fb < 2) ? (h*32 + fb*16)
              : (fb < 4) ? (256 + h*32 + (fb-2)*16)
                         : (512 + h*32 + (fb-4)*16);
    int row = rbase + (l & 15);
    int col = kk*32 + (l >> 4)*8;
    const float* src = qkv_w + row*CD + col;
    unsigned short* dst = wqkv + (size_t)t*8;
    #pragma unroll
    for (int j2 = 0; j2 < 8; ++j2) dst[j2] = f2bf(src[j2]);
  }
  if (t < 8*16*64) {                       // proj_w fragments
    int l  = t & 63;
    int fb = (t >> 6) & 15;
    int kk = t >> 10;
    int row = fb*16 + (l & 15);
    int col = kk*32 + (l >> 4)*8;
    const float* src = proj_w + row*CD + col;
    unsigned short* dst = wproj + (size_t)t*8;
    #pragma unroll
    for (int j2 = 0; j2 < 8; ++j2) dst[j2] = f2bf(src[j2]);
  }
  if (t < 8*64*64) {                       // bias, j-major, padded
    int i = t & 63, j = (t >> 6) & 63, h = t >> 12;
    float v = -10000.0f;
    if (j < WN) {
      int ii = i < WN ? i : WN - 1;        // i>=49 columns are discarded later
      v = rpb[relidx[ii*WN + j]*NH + h];
    }
    biasm[t] = v;
  }
  if (t < 64*64*64) {                      // mask, j-major, padded with 0
    int i = t & 63, j = (t >> 6) & 63, mw = t >> 12;
    maskp[t] = (i < WN && j < WN) ? mask[mw*WN*WN + i*WN + j] : 0.0f;
  }
}

// LDS: [0,32768)  XB: x bf16 [64][256], swizzle byte^=((row&7)<<4)
//                 later: per-wave V^T [32][64] at +w*4096 (swz (d&7)<<4), then O [64][256]
// [32768,98304)  per-wave 8 KB: Q[64][32]@+0, K@+4096 (swz ((tok>>1)&3)<<4);
//                 later P[64][64] bf16 over Q/K (swz (i&7)<<4)
__global__ __launch_bounds__(512) void wattn_fused(
    const float* __restrict__ x,
    const float* __restrict__ qkvb,
    const float* __restrict__ projb,
    const unsigned short* __restrict__ wqkv,
    const unsigned short* __restrict__ wproj,
    const float* __restrict__ biasm,
    const float* __restrict__ maskp,
    float* __restrict__ out)
{
  __shared__ char smem[98304] __attribute__((aligned(16)));
  const int tid = threadIdx.x;
  const int w  = tid >> 6;     // wave = head
  const int l  = tid & 63;
  const int lg = l >> 4;
  const int ll = l & 15;
  const int blk = blockIdx.x;
  const int xsw = (ll & 7) << 4;
  const f32x4 Z4 = {0.f, 0.f, 0.f, 0.f};

  // ---- stage x (fp32 -> bf16, swizzled), rows 49..63 zeroed ----
  {
    int row = tid >> 3, seg = tid & 7;
    char* dst = smem + row*512;
    int cb = seg*64;
    int sw = (row & 7) << 4;
    if (row < WN) {
      const float4* s4 = (const float4*)(x + (size_t)blk*WN*CD + row*CD + seg*32);
      #pragma unroll
      for (int q = 0; q < 4; ++q) {
        float4 a = s4[2*q], b = s4[2*q+1];
        uint4 u;
        u.x = pk2(a.x, a.y); u.y = pk2(a.z, a.w);
        u.z = pk2(b.x, b.y); u.w = pk2(b.z, b.w);
        *(uint4*)(dst + ((cb + q*16) ^ sw)) = u;
      }
    } else {
      uint4 z = {0u,0u,0u,0u};
      #pragma unroll
      for (int q = 0; q < 4; ++q) *(uint4*)(dst + ((cb + q*16) ^ sw)) = z;
    }
  }
  __syncthreads();

  // ---- qkv GEMM: q,k (64x32) and v^T (32x64) for head w ----
  f32x4 aq[4][2], ak[4][2], av[2][4];
  #pragma unroll
  for (int a = 0; a < 4; ++a)
    #pragma unroll
    for (int b = 0; b < 2; ++b) { aq[a][b] = Z4; ak[a][b] = Z4; av[b][a] = Z4; }

  const uint4* wsrc = (const uint4*)wqkv + (size_t)(w*8)*384 + l;  // + kk*384 + fb*64
  uint4 wbuf[6];
  #pragma unroll
  for (int fb = 0; fb < 6; ++fb) wbuf[fb] = wsrc[fb*64];

  for (int kk = 0; kk < 8; ++kk) {
    bf16x8 wf[6], xf[4];
    #pragma unroll
    for (int fb = 0; fb < 6; ++fb) wf[fb] = *(const bf16x8*)&wbuf[fb];
    if (kk < 7) {
      const uint4* nx = wsrc + (kk+1)*384;
      #pragma unroll
      for (int fb = 0; fb < 6; ++fb) wbuf[fb] = nx[fb*64];
    }
    #pragma unroll
    for (int mt = 0; mt < 4; ++mt)
      xf[mt] = *(const bf16x8*)(smem + (mt*16 + ll)*512 + ((kk*64 + lg*16) ^ xsw));
    #pragma unroll
    for (int mt = 0; mt < 4; ++mt) {
      aq[mt][0] = MFMA16(xf[mt], wf[0], aq[mt][0]);
      aq[mt][1] = MFMA16(xf[mt], wf[1], aq[mt][1]);
      ak[mt][0] = MFMA16(xf[mt], wf[2], ak[mt][0]);
      ak[mt][1] = MFMA16(xf[mt], wf[3], ak[mt][1]);
    }
    #pragma unroll
    for (int tm = 0; tm < 2; ++tm)
      #pragma unroll
      for (int tt = 0; tt < 4; ++tt)
        av[tm][tt] = MFMA16(wf[4+tm], xf[tt], av[tm][tt]);
  }

  // ---- add qkv bias; write Q,K token-major (swz ((tok>>1)&3)<<4) ----
  char* Qb = smem + 32768 + w*8192;
  char* Kb = Qb + 4096;
  {
    float bq0 = qkvb[w*32 + ll],       bq1 = qkvb[w*32 + 16 + ll];
    float bk0 = qkvb[256 + w*32 + ll], bk1 = qkvb[256 + w*32 + 16 + ll];
    #pragma unroll
    for (int mt = 0; mt < 4; ++mt)
      #pragma unroll
      for (int r = 0; r < 4; ++r) {
        int tok = mt*16 + lg*4 + r;
        int sw2 = ((tok >> 1) & 3) << 4;
        int base = tok*64;
        *(unsigned short*)(Qb + ((base + ll*2)      ^ sw2)) = f2bf(aq[mt][0][r] + bq0);
        *(unsigned short*)(Qb + ((base + (16+ll)*2) ^ sw2)) = f2bf(aq[mt][1][r] + bq1);
        *(unsigned short*)(Kb + ((base + ll*2)      ^ sw2)) = f2bf(ak[mt][0][r] + bk0);
        *(unsigned short*)(Kb + ((base + (16+ll)*2) ^ sw2)) = f2bf(ak[mt][1][r] + bk1);
      }
  }
  float bvv[2][4];
  #pragma unroll
  for (int tm = 0; tm < 2; ++tm)
    #pragma unroll
    for (int r = 0; r < 4; ++r)
      bvv[tm][r] = qkvb[512 + w*32 + tm*16 + lg*4 + r];

  __syncthreads();   // all waves done reading x -> XB reusable as V^T

  char* Vb = smem + w*4096;       // V^T [32 d][64 tok], swz (d&7)<<4
  #pragma unroll
  for (int tm = 0; tm < 2; ++tm)
    #pragma unroll
    for (int tt = 0; tt < 4; ++tt)
      #pragma unroll
      for (int r = 0; r < 4; ++r) {
        int d = tm*16 + lg*4 + r;
        *(unsigned short*)(Vb + ((d*128 + (tt*16 + ll)*2) ^ ((d & 7) << 4)))
            = f2bf(av[tm][tt][r] + bvv[tm][r]);
      }

  // ---- S^T = K * Q^T (64x64), one MFMA per tile (K=32=hd) ----
  f32x4 st[4][4];
  #pragma unroll
  for (int a = 0; a < 4; ++a)
    #pragma unroll
    for (int b = 0; b < 4; ++b) st[a][b] = Z4;
  {
    bf16x8 fk[4], fq[4];
    #pragma unroll
    for (int t = 0; t < 4; ++t) {
      int j = t*16 + ll;
      int sw2 = ((j >> 1) & 3) << 4;
      fk[t] = *(const bf16x8*)(Kb + ((j*64 + lg*16) ^ sw2));
      fq[t] = *(const bf16x8*)(Qb + ((j*64 + lg*16) ^ sw2));
    }
    #pragma unroll
    for (int tr = 0; tr < 4; ++tr)
      #pragma unroll
      for (int tc = 0; tc < 4; ++tc)
        st[tr][tc] = MFMA16(fk[tr], fq[tc], st[tr][tc]);
  }

  // ---- softmax over j (per column i), bias+mask from padded j-major tables ----
  const float scale = 0.17677669529663687f;   // 32^-0.5
  const float* bh = biasm + w*4096;
  const float* mh = maskp + (size_t)(blk & 63)*4096;
  #pragma unroll
  for (int tr = 0; tr < 4; ++tr)
    #pragma unroll
    for (int tc = 0; tc < 4; ++tc)
      #pragma unroll
      for (int r = 0; r < 4; ++r) {
        int j = tr*16 + lg*4 + r, i = tc*16 + ll;
        st[tr][tc][r] = st[tr][tc][r]*scale + bh[j*64 + i] + mh[j*64 + i];
      }
  float invl[4];
  #pragma unroll
  for (int tc = 0; tc < 4; ++tc) {
    float m = -3.0e38f;
    #pragma unroll
    for (int tr = 0; tr < 4; ++tr)
      #pragma unroll
      for (int r = 0; r < 4; ++r) m = fmaxf(m, st[tr][tc][r]);
    m = fmaxf(m, __shfl_xor(m, 16));
    m = fmaxf(m, __shfl_xor(m, 32));
    float s = 0.f;
    #pragma unroll
    for (int tr = 0; tr < 4; ++tr)
      #pragma unroll
      for (int r = 0; r < 4; ++r) {
        float p = __expf(st[tr][tc][r] - m);
        st[tr][tc][r] = p;
        s += p;
      }
    s += __shfl_xor(s, 16);
    s += __shfl_xor(s, 32);
    invl[tc] = 1.0f / s;          // normalization deferred to O
  }

  // ---- write P [i][j] bf16 over Q/K (swz (i&7)<<4), unnormalized ----
  char* Pb = Qb;
  #pragma unroll
  for (int tc = 0; tc < 4; ++tc) {
    int i = tc*16 + ll;
    int isw = (i & 7) << 4;
    #pragma unroll
    for (int tr = 0; tr < 4; ++tr) {
      uint2 u;
      u.x = pk2(st[tr][tc][0], st[tr][tc][1]);
      u.y = pk2(st[tr][tc][2], st[tr][tc][3]);
      *(uint2*)(Pb + ((i*128 + (tr*16 + lg*4)*2) ^ isw)) = u;
    }
  }

  // ---- PV: O^T = V^T * P (32x64) ----
  f32x4 ot[2][4];
  #pragma unroll
  for (int a = 0; a < 2; ++a)
    #pragma unroll
    for (int b = 0; b < 4; ++b) ot[a][b] = Z4;
  #pragma unroll
  for (int ks = 0; ks < 2; ++ks) {
    bf16x8 fv[2], fp[4];
    #pragma unroll
    for (int tm = 0; tm < 2; ++tm) {
      int d = tm*16 + ll;
      fv[tm] = *(const bf16x8*)(smem + w*4096 + ((d*128 + (ks*32 + lg*8)*2) ^ ((d & 7) << 4)));
    }
    #pragma unroll
    for (int tn = 0; tn < 4; ++tn) {
      int i = tn*16 + ll;
      fp[tn] = *(const bf16x8*)(Pb + ((i*128 + (ks*32 + lg*8)*2) ^ ((i & 7) << 4)));
    }
    #pragma unroll
    for (int tm = 0; tm < 2; ++tm)
      #pragma unroll
      for (int tn = 0; tn < 4; ++tn)
        ot[tm][tn] = MFMA16(fv[tm], fp[tn], ot[tm][tn]);
  }

  __syncthreads();   // all PV reads of V^T done -> XB reusable as O

  // ---- write O [i][w*32+d] bf16 into XB (swz (i&7)<<4), normalized ----
  #pragma unroll
  for (int tn = 0; tn < 4; ++tn) {
    int i = tn*16 + ll;
    int isw = (i & 7) << 4;
    #pragma unroll
    for (int tm = 0; tm < 2; ++tm) {
      uint2 u;
      u.x = pk2(ot[tm][tn][0]*invl[tn], ot[tm][tn][1]*invl[tn]);
      u.y = pk2(ot[tm][tn][2]*invl[tn], ot[tm][tn][3]*invl[tn]);
      *(uint2*)(smem + ((i*512 + (w*32 + tm*16 + lg*4)*2) ^ isw)) = u;
    }
  }
  __syncthreads();

  // ---- proj GEMM: out = O @ proj_w^T + proj_b; wave w -> cols [32w,32w+32) ----
  f32x4 ap[4][2];
  #pragma unroll
  for (int a = 0; a < 4; ++a) { ap[a][0] = Z4; ap[a][1] = Z4; }
  const uint4* psrc = (const uint4*)wproj + l;     // + (kk*16+fb)*64
  uint4 pbuf[2];
  pbuf[0] = psrc[(2*w)*64];
  pbuf[1] = psrc[(2*w + 1)*64];
  for (int kk = 0; kk < 8; ++kk) {
    bf16x8 bfr0 = *(const bf16x8*)&pbuf[0];
    bf16x8 bfr1 = *(const bf16x8*)&pbuf[1];
    if (kk < 7) {
      pbuf[0] = psrc[((kk+1)*16 + 2*w)*64];
      pbuf[1] = psrc[((kk+1)*16 + 2*w + 1)*64];
    }
    bf16x8 af[4];
    #pragma unroll
    for (int mt = 0; mt < 4; ++mt) {
      int i = mt*16 + ll;
      af[mt] = *(const bf16x8*)(smem + ((i*512 + kk*64 + lg*16) ^ ((i & 7) << 4)));
    }
    #pragma unroll
    for (int mt = 0; mt < 4; ++mt) {
      ap[mt][0] = MFMA16(af[mt], bfr0, ap[mt][0]);
      ap[mt][1] = MFMA16(af[mt], bfr1, ap[mt][1]);
    }
  }

  float pb0 = projb[w*32 + ll], pb1 = projb[w*32 + 16 + ll];
  float* op = out + (size_t)blk*WN*CD;
  #pragma unroll
  for (int mt = 0; mt < 4; ++mt)
    #pragma unroll
    for (int r = 0; r < 4; ++r) {
      int i = mt*16 + lg*4 + r;
      if (i < WN) {
        op[i*CD + w*32 + ll]      = ap[mt][0][r] + pb0;
        op[i*CD + w*32 + 16 + ll] = ap[mt][1][r] + pb1;
      }
    }
}

extern "C" void kernel_launch(void* const* d_in, const int* in_sizes, int n_in,
                              void* d_out, int out_size, void* d_ws, size_t ws_size,
                              hipStream_t stream) {
  const float* x      = (const float*)d_in[0];
  const float* mask   = (const float*)d_in[1];
  const float* qkv_w  = (const float*)d_in[2];
  const float* qkv_b  = (const float*)d_in[3];
  const float* proj_w = (const float*)d_in[4];
  const float* proj_b = (const float*)d_in[5];
  const float* rpb    = (const float*)d_in[6];
  const int*   relidx = (const int*)d_in[7];

  char* ws = (char*)d_ws;
  unsigned short* wqkv  = (unsigned short*)(ws + WS_WQKV);
  unsigned short* wproj = (unsigned short*)(ws + WS_WPROJ);
  float* biasm = (float*)(ws + WS_BIAS);
  float* maskp = (float*)(ws + WS_MASK);
  float* out = (float*)d_out;

  prep_kernel<<<1024, 256, 0, stream>>>(qkv_w, proj_w, rpb, relidx, mask,
                                        wqkv, wproj, biasm, maskp);
  wattn_fused<<<4096, 512, 0, stream>>>(x, qkv_b, proj_b, wqkv, wproj,
                                        biasm, maskp, out);
}

// Round 2
// 321.577 us; speedup vs baseline: 1.0015x; 1.0015x over previous
//
#include <hip/hip_runtime.h>
#include <stdint.h>

// Fused Swin window-attention, MI355X gfx950.  v2: in-register attention.
// One workgroup (512 thr = 8 waves) per window; wave w = head w.
// qkv/proj GEMMs: mfma_f32_16x16x32_bf16 (LDS x-tile + fragment-major weights).
// QK^T and PV: mfma_f32_16x16x16_f16 with acc->frag identity lane mapping:
//   Q^T,K^T computed channel-major, V token-major => S^T = K*Q^T and
//   O^T = V^T*P consume previous accumulators directly (no LDS round trip).
// LDS = 32 KB (x tile, reused for O) -> 2 blocks/CU at 128 VGPR.

#define WN 49      // tokens per window
#define CD 256     // channels
#define NH 8       // heads

typedef float    f32x4  __attribute__((ext_vector_type(4)));
typedef short    bf16x8 __attribute__((ext_vector_type(8)));
typedef _Float16 half4  __attribute__((ext_vector_type(4)));

#define MFMA32(a,b,c)  __builtin_amdgcn_mfma_f32_16x16x32_bf16((a),(b),(c),0,0,0)
#define MFMA16H(a,b,c) __builtin_amdgcn_mfma_f32_16x16x16f16((a),(b),(c),0,0,0)

__device__ __forceinline__ unsigned short f2bf(float f) {
  union { float f; unsigned u; } c; c.f = f;
  unsigned x = c.u;
  x += 0x7FFFu + ((x >> 16) & 1u);          // round-to-nearest-even
  return (unsigned short)(x >> 16);
}
__device__ __forceinline__ unsigned pk2(float a, float b) {
  union { float f; unsigned u; } ca, cb; ca.f = a; cb.f = b;
  unsigned xx = ca.u, yy = cb.u;
  xx += 0x7FFFu + ((xx >> 16) & 1u);
  yy += 0x7FFFu + ((yy >> 16) & 1u);
  return (xx >> 16) | (yy & 0xFFFF0000u);
}

// ---------------- workspace layout (bytes) ----------------
// WQKV : [8 h][8 kk][6 fb][64 lane][8 bf16]  fragment-major qkv_w   = 393216
// WPROJ: [8 kk][16 fb][64 lane][8 bf16]      fragment-major proj_w  = 131072
// BIAS : [8 h][64 j][64 i] f32 (j>=49 -> -1e4)                      = 131072
// MASK : [64 w][64 j][64 i] f32 (padded with 0)                     = 1048576
#define WS_WQKV  0
#define WS_WPROJ 393216
#define WS_BIAS  524288
#define WS_MASK  655360

__global__ __launch_bounds__(256) void prep_kernel(
    const float* __restrict__ qkv_w, const float* __restrict__ proj_w,
    const float* __restrict__ rpb,   const int*   __restrict__ relidx,
    const float* __restrict__ mask,
    unsigned short* __restrict__ wqkv, unsigned short* __restrict__ wproj,
    float* __restrict__ biasm, float* __restrict__ maskp)
{
  int t = blockIdx.x * blockDim.x + threadIdx.x;
  if (t < 8*8*6*64) {                      // qkv_w fragments, head-grouped rows
    int l    = t & 63;
    int fb   = (t >> 6) % 6;
    int rest = t / (64*6);
    int kk = rest & 7, h = rest >> 3;
    int rbase = (fb < 2) ? (h*32 + fb*16)
              : (fb < 4) ? (256 + h*32 + (fb-2)*16)
                         : (512 + h*32 + (fb-4)*16);
    int row = rbase + (l & 15);
    int col = kk*32 + (l >> 4)*8;
    const float* src = qkv_w + row*CD + col;
    unsigned short* dst = wqkv + (size_t)t*8;
    #pragma unroll
    for (int j2 = 0; j2 < 8; ++j2) dst[j2] = f2bf(src[j2]);
  }
  if (t < 8*16*64) {                       // proj_w fragments
    int l  = t & 63;
    int fb = (t >> 6) & 15;
    int kk = t >> 10;
    int row = fb*16 + (l & 15);
    int col = kk*32 + (l >> 4)*8;
    const float* src = proj_w + row*CD + col;
    unsigned short* dst = wproj + (size_t)t*8;
    #pragma unroll
    for (int j2 = 0; j2 < 8; ++j2) dst[j2] = f2bf(src[j2]);
  }
  if (t < 8*64*64) {                       // bias, j-major, padded
    int i = t & 63, j = (t >> 6) & 63, h = t >> 12;
    float v = -10000.0f;
    if (j < WN) {
      int ii = i < WN ? i : WN - 1;        // i>=49 columns are discarded later
      v = rpb[relidx[ii*WN + j]*NH + h];
    }
    biasm[t] = v;
  }
  if (t < 64*64*64) {                      // mask, j-major, padded with 0
    int i = t & 63, j = (t >> 6) & 63, mw = t >> 12;
    maskp[t] = (i < WN && j < WN) ? mask[mw*WN*WN + i*WN + j] : 0.0f;
  }
}

// LDS: 32 KB. Phase 1: x bf16 [64 tok][256 ch], byte-swizzle ^((row&7)<<4).
//              Phase 2 (after barrier): O bf16 [64 tok][256 ch], same swizzle.
__global__ __launch_bounds__(512, 4) void wattn_fused(
    const float* __restrict__ x,
    const float* __restrict__ qkvb,
    const float* __restrict__ projb,
    const unsigned short* __restrict__ wqkv,
    const unsigned short* __restrict__ wproj,
    const float* __restrict__ biasm,
    const float* __restrict__ maskp,
    float* __restrict__ out)
{
  __shared__ char smem[32768] __attribute__((aligned(16)));
  const int tid = threadIdx.x;
  const int w  = tid >> 6;     // wave = head
  const int l  = tid & 63;
  const int lg = l >> 4;
  const int ll = l & 15;
  const int blk = blockIdx.x;
  const int xsw = (ll & 7) << 4;
  const f32x4 Z4 = {0.f, 0.f, 0.f, 0.f};

  // ---- stage x (fp32 -> bf16, swizzled), rows 49..63 zeroed ----
  {
    int row = tid >> 3, seg = tid & 7;
    char* dst = smem + row*512;
    int cb = seg*64;
    int sw = (row & 7) << 4;
    if (row < WN) {
      const float4* s4 = (const float4*)(x + (size_t)blk*WN*CD + row*CD + seg*32);
      #pragma unroll
      for (int q = 0; q < 4; ++q) {
        float4 a = s4[2*q], b = s4[2*q+1];
        uint4 u;
        u.x = pk2(a.x, a.y); u.y = pk2(a.z, a.w);
        u.z = pk2(b.x, b.y); u.w = pk2(b.z, b.w);
        *(uint4*)(dst + ((cb + q*16) ^ sw)) = u;
      }
    } else {
      uint4 z = {0u,0u,0u,0u};
      #pragma unroll
      for (int q = 0; q < 4; ++q) *(uint4*)(dst + ((cb + q*16) ^ sw)) = z;
    }
  }
  __syncthreads();

  const uint4* wsrc = (const uint4*)wqkv + (size_t)(w*8)*384 + l;  // +kk*384+fb*64

  // ---- qkv pass 1: Q^T, K^T (channel-major) ----
  // A = W fragment (rows = out-channels), B = x fragment (cols = tokens).
  // acc: col(lane&15)=token, row((lane>>4)*4+r)=out-channel within 16-tile.
  f32x4 aq[2][4], ak[2][4];
  #pragma unroll
  for (int a = 0; a < 2; ++a)
    #pragma unroll
    for (int b = 0; b < 4; ++b) { aq[a][b] = Z4; ak[a][b] = Z4; }

  #pragma unroll 2
  for (int kk = 0; kk < 8; ++kk) {
    uint4 wb[4];
    #pragma unroll
    for (int fb = 0; fb < 4; ++fb) wb[fb] = wsrc[kk*384 + fb*64];
    bf16x8 xf[4];
    #pragma unroll
    for (int tt = 0; tt < 4; ++tt)
      xf[tt] = *(const bf16x8*)(smem + (tt*16 + ll)*512 + ((kk*64 + lg*16) ^ xsw));
    bf16x8 wq0 = *(const bf16x8*)&wb[0], wq1 = *(const bf16x8*)&wb[1];
    bf16x8 wk0 = *(const bf16x8*)&wb[2], wk1 = *(const bf16x8*)&wb[3];
    #pragma unroll
    for (int tt = 0; tt < 4; ++tt) {
      aq[0][tt] = MFMA32(wq0, xf[tt], aq[0][tt]);
      aq[1][tt] = MFMA32(wq1, xf[tt], aq[1][tt]);
      ak[0][tt] = MFMA32(wk0, xf[tt], ak[0][tt]);
      ak[1][tt] = MFMA32(wk1, xf[tt], ak[1][tt]);
    }
  }

  // bias + cvt to f16 frags (scale folded into K). Frees aq/ak.
  const float scale = 0.17677669529663687f;   // 32^-0.5
  half4 qf[2][4], kf[2][4];
  #pragma unroll
  for (int ds = 0; ds < 2; ++ds) {
    f32x4 bq = *(const f32x4*)(qkvb + w*32 + ds*16 + lg*4);
    f32x4 bk = *(const f32x4*)(qkvb + 256 + w*32 + ds*16 + lg*4);
    #pragma unroll
    for (int tt = 0; tt < 4; ++tt)
      #pragma unroll
      for (int e = 0; e < 4; ++e) {
        qf[ds][tt][e] = (_Float16)(aq[ds][tt][e] + bq[e]);
        kf[ds][tt][e] = (_Float16)((ak[ds][tt][e] + bk[e]) * scale);
      }
  }

  // ---- qkv pass 2: V (token-major) ----
  // acc: col(lane&15)=v-channel within 16-tile, row=token.
  f32x4 av[4][2];
  #pragma unroll
  for (int a = 0; a < 4; ++a) { av[a][0] = Z4; av[a][1] = Z4; }
  #pragma unroll 2
  for (int kk = 0; kk < 8; ++kk) {
    uint4 wb0 = wsrc[kk*384 + 4*64];
    uint4 wb1 = wsrc[kk*384 + 5*64];
    bf16x8 xf[4];
    #pragma unroll
    for (int tt = 0; tt < 4; ++tt)
      xf[tt] = *(const bf16x8*)(smem + (tt*16 + ll)*512 + ((kk*64 + lg*16) ^ xsw));
    bf16x8 wv0 = *(const bf16x8*)&wb0, wv1 = *(const bf16x8*)&wb1;
    #pragma unroll
    for (int tt = 0; tt < 4; ++tt) {
      av[tt][0] = MFMA32(xf[tt], wv0, av[tt][0]);
      av[tt][1] = MFMA32(xf[tt], wv1, av[tt][1]);
    }
  }
  // v bias + cvt -> PV A-frags (V^T): vf[ds][jt], row=d(lane&15), k=token. Frees av.
  half4 vf[2][4];
  {
    float bv0 = qkvb[512 + w*32 + ll];
    float bv1 = qkvb[512 + w*32 + 16 + ll];
    #pragma unroll
    for (int tt = 0; tt < 4; ++tt)
      #pragma unroll
      for (int e = 0; e < 4; ++e) {
        vf[0][tt][e] = (_Float16)(av[tt][0][e] + bv0);
        vf[1][tt][e] = (_Float16)(av[tt][1][e] + bv1);
      }
  }

  // ---- S^T = K * Q^T (64x64) fully in-register ----
  f32x4 st[4][4];
  #pragma unroll
  for (int a = 0; a < 4; ++a)
    #pragma unroll
    for (int b = 0; b < 4; ++b) st[a][b] = Z4;
  #pragma unroll
  for (int jt = 0; jt < 4; ++jt)
    #pragma unroll
    for (int it = 0; it < 4; ++it) {
      st[jt][it] = MFMA16H(kf[0][jt], qf[0][it], st[jt][it]);
      st[jt][it] = MFMA16H(kf[1][jt], qf[1][it], st[jt][it]);
    }

  // ---- bias + mask + softmax over j (keys). j=jt*16+lg*4+r, i=it*16+ll ----
  const float* bh = biasm + w*4096;
  const float* mh = maskp + (size_t)(blk & 63)*4096;
  #pragma unroll
  for (int jt = 0; jt < 4; ++jt)
    #pragma unroll
    for (int it = 0; it < 4; ++it)
      #pragma unroll
      for (int r = 0; r < 4; ++r) {
        int j = jt*16 + lg*4 + r, i = it*16 + ll;
        st[jt][it][r] += bh[j*64 + i] + mh[j*64 + i];
      }
  float invl[4];
  #pragma unroll
  for (int it = 0; it < 4; ++it) {
    float m = -3.0e38f;
    #pragma unroll
    for (int jt = 0; jt < 4; ++jt)
      #pragma unroll
      for (int r = 0; r < 4; ++r) m = fmaxf(m, st[jt][it][r]);
    m = fmaxf(m, __shfl_xor(m, 16));
    m = fmaxf(m, __shfl_xor(m, 32));
    float s = 0.f;
    #pragma unroll
    for (int jt = 0; jt < 4; ++jt)
      #pragma unroll
      for (int r = 0; r < 4; ++r) {
        float p = __expf(st[jt][it][r] - m);
        st[jt][it][r] = p;
        s += p;
      }
    s += __shfl_xor(s, 16);
    s += __shfl_xor(s, 32);
    invl[it] = 1.0f / s;          // normalization deferred to O
  }

  // ---- P frags (PV B-operand) directly from S^T acc ----
  half4 pf[4][4];
  #pragma unroll
  for (int jt = 0; jt < 4; ++jt)
    #pragma unroll
    for (int it = 0; it < 4; ++it)
      #pragma unroll
      for (int e = 0; e < 4; ++e)
        pf[jt][it][e] = (_Float16)st[jt][it][e];

  // ---- PV: O^T = V^T * P. acc: col=token i, row=d within 16-tile ----
  f32x4 ot[2][4];
  #pragma unroll
  for (int a = 0; a < 2; ++a)
    #pragma unroll
    for (int b = 0; b < 4; ++b) ot[a][b] = Z4;
  #pragma unroll
  for (int dt = 0; dt < 2; ++dt)
    #pragma unroll
    for (int it = 0; it < 4; ++it)
      #pragma unroll
      for (int jt = 0; jt < 4; ++jt)
        ot[dt][it] = MFMA16H(vf[dt][jt], pf[jt][it], ot[dt][it]);

  __syncthreads();   // all x reads done -> smem reusable as O

  // ---- write O [i][c] bf16 (swz (i&7)<<4), normalized ----
  #pragma unroll
  for (int it = 0; it < 4; ++it) {
    int i = it*16 + ll;
    int isw = (i & 7) << 4;
    #pragma unroll
    for (int dt = 0; dt < 2; ++dt) {
      int c0 = w*32 + dt*16 + lg*4;
      uint2 u;
      u.x = pk2(ot[dt][it][0]*invl[it], ot[dt][it][1]*invl[it]);
      u.y = pk2(ot[dt][it][2]*invl[it], ot[dt][it][3]*invl[it]);
      *(uint2*)(smem + i*512 + ((c0*2) ^ isw)) = u;
    }
  }
  __syncthreads();

  // ---- proj GEMM: out = O @ proj_w^T + proj_b; wave w -> cols [32w,32w+32) ----
  f32x4 ap[4][2];
  #pragma unroll
  for (int a = 0; a < 4; ++a) { ap[a][0] = Z4; ap[a][1] = Z4; }
  const uint4* psrc = (const uint4*)wproj + l;     // + (kk*16+fb)*64
  uint4 pbuf[2];
  pbuf[0] = psrc[(2*w)*64];
  pbuf[1] = psrc[(2*w + 1)*64];
  #pragma unroll 2
  for (int kk = 0; kk < 8; ++kk) {
    bf16x8 bfr0 = *(const bf16x8*)&pbuf[0];
    bf16x8 bfr1 = *(const bf16x8*)&pbuf[1];
    if (kk < 7) {
      pbuf[0] = psrc[((kk+1)*16 + 2*w)*64];
      pbuf[1] = psrc[((kk+1)*16 + 2*w + 1)*64];
    }
    bf16x8 af[4];
    #pragma unroll
    for (int mt = 0; mt < 4; ++mt) {
      int i = mt*16 + ll;
      af[mt] = *(const bf16x8*)(smem + ((i*512 + kk*64 + lg*16) ^ ((i & 7) << 4)));
    }
    #pragma unroll
    for (int mt = 0; mt < 4; ++mt) {
      ap[mt][0] = MFMA32(af[mt], bfr0, ap[mt][0]);
      ap[mt][1] = MFMA32(af[mt], bfr1, ap[mt][1]);
    }
  }

  float pb0 = projb[w*32 + ll], pb1 = projb[w*32 + 16 + ll];
  float* op = out + (size_t)blk*WN*CD;
  #pragma unroll
  for (int mt = 0; mt < 4; ++mt)
    #pragma unroll
    for (int r = 0; r < 4; ++r) {
      int i = mt*16 + lg*4 + r;
      if (i < WN) {
        op[i*CD + w*32 + ll]      = ap[mt][0][r] + pb0;
        op[i*CD + w*32 + 16 + ll] = ap[mt][1][r] + pb1;
      }
    }
}

extern "C" void kernel_launch(void* const* d_in, const int* in_sizes, int n_in,
                              void* d_out, int out_size, void* d_ws, size_t ws_size,
                              hipStream_t stream) {
  const float* x      = (const float*)d_in[0];
  const float* mask   = (const float*)d_in[1];
  const float* qkv_w  = (const float*)d_in[2];
  const float* qkv_b  = (const float*)d_in[3];
  const float* proj_w = (const float*)d_in[4];
  const float* proj_b = (const float*)d_in[5];
  const float* rpb    = (const float*)d_in[6];
  const int*   relidx = (const int*)d_in[7];

  char* ws = (char*)d_ws;
  unsigned short* wqkv  = (unsigned short*)(ws + WS_WQKV);
  unsigned short* wproj = (unsigned short*)(ws + WS_WPROJ);
  float* biasm = (float*)(ws + WS_BIAS);
  float* maskp = (float*)(ws + WS_MASK);
  float* out = (float*)d_out;

  prep_kernel<<<1024, 256, 0, stream>>>(qkv_w, proj_w, rpb, relidx, mask,
                                        wqkv, wproj, biasm, maskp);
  wattn_fused<<<4096, 512, 0, stream>>>(x, qkv_b, proj_b, wqkv, wproj,
                                        biasm, maskp, out);
}

// Round 3
// 246.165 us; speedup vs baseline: 1.3083x; 1.3064x over previous
//
#include <hip/hip_runtime.h>
#include <stdint.h>

// Fused Swin window-attention, MI355X gfx950.  v3: spill-free phase order +
// combined bias/mask table + no-max exp2 softmax.
// One workgroup (512 thr = 8 waves) per window; wave w = head w.
// Phase order: stage x -> QK^T proj -> S -> softmax -> P frags -> V proj ->
// PV -> O to LDS -> proj GEMM.  V pass moved after softmax so its fragments
// are not live across the register-peak softmax phase (kills scratch spills).

#define WN 49      // tokens per window
#define CD 256     // channels
#define NH 8       // heads

typedef float    f32x4  __attribute__((ext_vector_type(4)));
typedef short    bf16x8 __attribute__((ext_vector_type(8)));
typedef _Float16 half4  __attribute__((ext_vector_type(4)));

#define MFMA32(a,b,c)  __builtin_amdgcn_mfma_f32_16x16x32_bf16((a),(b),(c),0,0,0)
#define MFMA16H(a,b,c) __builtin_amdgcn_mfma_f32_16x16x16f16((a),(b),(c),0,0,0)

__device__ __forceinline__ unsigned short f2bf(float f) {
  union { float f; unsigned u; } c; c.f = f;
  unsigned x = c.u;
  x += 0x7FFFu + ((x >> 16) & 1u);          // round-to-nearest-even
  return (unsigned short)(x >> 16);
}
__device__ __forceinline__ unsigned pk2(float a, float b) {
  union { float f; unsigned u; } ca, cb; ca.f = a; cb.f = b;
  unsigned xx = ca.u, yy = cb.u;
  xx += 0x7FFFu + ((xx >> 16) & 1u);
  yy += 0x7FFFu + ((yy >> 16) & 1u);
  return (xx >> 16) | (yy & 0xFFFF0000u);
}
__device__ __forceinline__ float bfhi(unsigned u) {   // high bf16 -> f32
  union { unsigned u; float f; } c; c.u = u & 0xFFFF0000u; return c.f;
}
__device__ __forceinline__ float bflo(unsigned u) {   // low bf16 -> f32
  union { unsigned u; float f; } c; c.u = u << 16; return c.f;
}

// ---------------- workspace layout (bytes) ----------------
// WQKV : [8 h][8 kk][6 fb][64 lane][8 bf16]  fragment-major qkv_w   = 393216
// WPROJ: [8 kk][16 fb][64 lane][8 bf16]      fragment-major proj_w  = 131072
// TBL  : [64 w][8 h][64 i][64 j] bf16 = (bias+mask)*log2e, j>=49 -> -21640
//                                                                  = 4194304
#define WS_WQKV  0
#define WS_WPROJ 393216
#define WS_TBL   524288

__global__ __launch_bounds__(256) void prep_kernel(
    const float* __restrict__ qkv_w, const float* __restrict__ proj_w,
    const float* __restrict__ rpb,   const int*   __restrict__ relidx,
    const float* __restrict__ mask,
    unsigned short* __restrict__ wqkv, unsigned short* __restrict__ wproj,
    unsigned short* __restrict__ tblw)
{
  int t = blockIdx.x * blockDim.x + threadIdx.x;
  if (t < 8*8*6*64) {                      // qkv_w fragments, head-grouped rows
    int l    = t & 63;
    int fb   = (t >> 6) % 6;
    int rest = t / (64*6);
    int kk = rest & 7, h = rest >> 3;
    int rbase = (fb < 2) ? (h*32 + fb*16)
              : (fb < 4) ? (256 + h*32 + (fb-2)*16)
                         : (512 + h*32 + (fb-4)*16);
    int row = rbase + (l & 15);
    int col = kk*32 + (l >> 4)*8;
    const float* src = qkv_w + row*CD + col;
    unsigned short* dst = wqkv + (size_t)t*8;
    #pragma unroll
    for (int j2 = 0; j2 < 8; ++j2) dst[j2] = f2bf(src[j2]);
  }
  if (t < 8*16*64) {                       // proj_w fragments
    int l  = t & 63;
    int fb = (t >> 6) & 15;
    int kk = t >> 10;
    int row = fb*16 + (l & 15);
    int col = kk*32 + (l >> 4)*8;
    const float* src = proj_w + row*CD + col;
    unsigned short* dst = wproj + (size_t)t*8;
    #pragma unroll
    for (int j2 = 0; j2 < 8; ++j2) dst[j2] = f2bf(src[j2]);
  }
  if (t < 64*8*64*64) {                    // combined (bias+mask)*log2e table
    int j = t & 63, i = (t >> 6) & 63, h = (t >> 12) & 7, mw = t >> 15;
    float v = -21640.0f;                   // padded keys: exp2 -> 0
    if (j < WN) {
      int ii = i < WN ? i : WN - 1;        // padded query cols: copy row 48
      v = (rpb[relidx[ii*WN + j]*NH + h] + mask[mw*WN*WN + ii*WN + j])
          * 1.4426950408889634f;
    }
    tblw[t] = f2bf(v);
  }
}

// LDS: 32 KB. Phase 1: x bf16 [64 tok][256 ch], byte-swizzle ^((row&7)<<4).
//              Phase 2 (after barrier): O bf16 [64 tok][256 ch], same swizzle.
__global__ __launch_bounds__(512, 4) void wattn_fused(
    const float* __restrict__ x,
    const float* __restrict__ qkvb,
    const float* __restrict__ projb,
    const unsigned short* __restrict__ wqkv,
    const unsigned short* __restrict__ wproj,
    const unsigned short* __restrict__ tbl,
    float* __restrict__ out)
{
  __shared__ char smem[32768] __attribute__((aligned(16)));
  const int tid = threadIdx.x;
  const int w  = tid >> 6;     // wave = head
  const int l  = tid & 63;
  const int lg = l >> 4;
  const int ll = l & 15;
  const int blk = blockIdx.x;
  const int xsw = (ll & 7) << 4;
  const f32x4 Z4 = {0.f, 0.f, 0.f, 0.f};

  // ---- stage x (fp32 -> bf16, swizzled), rows 49..63 zeroed ----
  {
    int row = tid >> 3, seg = tid & 7;
    char* dst = smem + row*512;
    int cb = seg*64;
    int sw = (row & 7) << 4;
    if (row < WN) {
      const float4* s4 = (const float4*)(x + (size_t)blk*WN*CD + row*CD + seg*32);
      #pragma unroll
      for (int q = 0; q < 4; ++q) {
        float4 a = s4[2*q], b = s4[2*q+1];
        uint4 u;
        u.x = pk2(a.x, a.y); u.y = pk2(a.z, a.w);
        u.z = pk2(b.x, b.y); u.w = pk2(b.z, b.w);
        *(uint4*)(dst + ((cb + q*16) ^ sw)) = u;
      }
    } else {
      uint4 z = {0u,0u,0u,0u};
      #pragma unroll
      for (int q = 0; q < 4; ++q) *(uint4*)(dst + ((cb + q*16) ^ sw)) = z;
    }
  }
  __syncthreads();

  const uint4* wsrc = (const uint4*)wqkv + (size_t)(w*8)*384 + l;  // +kk*384+fb*64

  // ---- qkv pass 1: Q^T, K^T (channel-major) ----
  // acc: col(lane&15)=token, row((lane>>4)*4+r)=out-channel within 16-tile.
  f32x4 aq[2][4], ak[2][4];
  #pragma unroll
  for (int a = 0; a < 2; ++a)
    #pragma unroll
    for (int b = 0; b < 4; ++b) { aq[a][b] = Z4; ak[a][b] = Z4; }

  #pragma unroll 2
  for (int kk = 0; kk < 8; ++kk) {
    uint4 wb[4];
    #pragma unroll
    for (int fb = 0; fb < 4; ++fb) wb[fb] = wsrc[kk*384 + fb*64];
    bf16x8 xf[4];
    #pragma unroll
    for (int tt = 0; tt < 4; ++tt)
      xf[tt] = *(const bf16x8*)(smem + (tt*16 + ll)*512 + ((kk*64 + lg*16) ^ xsw));
    bf16x8 wq0 = *(const bf16x8*)&wb[0], wq1 = *(const bf16x8*)&wb[1];
    bf16x8 wk0 = *(const bf16x8*)&wb[2], wk1 = *(const bf16x8*)&wb[3];
    #pragma unroll
    for (int tt = 0; tt < 4; ++tt) {
      aq[0][tt] = MFMA32(wq0, xf[tt], aq[0][tt]);
      aq[1][tt] = MFMA32(wq1, xf[tt], aq[1][tt]);
      ak[0][tt] = MFMA32(wk0, xf[tt], ak[0][tt]);
      ak[1][tt] = MFMA32(wk1, xf[tt], ak[1][tt]);
    }
  }

  // bias + cvt to f16 frags; scale*log2e folded into K. Frees aq/ak.
  const float kscale = 0.17677669529663687f * 1.4426950408889634f;
  half4 qf[2][4], kf[2][4];
  #pragma unroll
  for (int ds = 0; ds < 2; ++ds) {
    f32x4 bq = *(const f32x4*)(qkvb + w*32 + ds*16 + lg*4);
    f32x4 bk = *(const f32x4*)(qkvb + 256 + w*32 + ds*16 + lg*4);
    #pragma unroll
    for (int tt = 0; tt < 4; ++tt)
      #pragma unroll
      for (int e = 0; e < 4; ++e) {
        qf[ds][tt][e] = (_Float16)(aq[ds][tt][e] + bq[e]);
        kf[ds][tt][e] = (_Float16)((ak[ds][tt][e] + bk[e]) * kscale);
      }
  }

  // ---- S^T = K * Q^T (64x64) fully in-register ----
  f32x4 st[4][4];
  #pragma unroll
  for (int a = 0; a < 4; ++a)
    #pragma unroll
    for (int b = 0; b < 4; ++b) st[a][b] = Z4;
  #pragma unroll
  for (int jt = 0; jt < 4; ++jt)
    #pragma unroll
    for (int it = 0; it < 4; ++it) {
      st[jt][it] = MFMA16H(kf[0][jt], qf[0][it], st[jt][it]);
      st[jt][it] = MFMA16H(kf[1][jt], qf[1][it], st[jt][it]);
    }

  // ---- softmax (no max-sub): p = exp2(st + TBL), TBL = (bias+mask)*log2e ----
  // j = jt*16+lg*4+r (contiguous r), i = it*16+ll; table layout [i][j] bf16.
  const unsigned short* tb = tbl + ((size_t)((blk & 63)*8 + w) << 12);
  #pragma unroll
  for (int it = 0; it < 4; ++it) {
    int i = it*16 + ll;
    #pragma unroll
    for (int jt = 0; jt < 4; ++jt) {
      uint2 u = *(const uint2*)(tb + i*64 + jt*16 + lg*4);
      st[jt][it][0] = __builtin_amdgcn_exp2f(st[jt][it][0] + bflo(u.x));
      st[jt][it][1] = __builtin_amdgcn_exp2f(st[jt][it][1] + bfhi(u.x));
      st[jt][it][2] = __builtin_amdgcn_exp2f(st[jt][it][2] + bflo(u.y));
      st[jt][it][3] = __builtin_amdgcn_exp2f(st[jt][it][3] + bfhi(u.y));
    }
  }

  // ---- row sums + normalize + cvt -> P frags (PV B-operand) ----
  half4 pf[4][4];
  #pragma unroll
  for (int it = 0; it < 4; ++it) {
    float s = 0.f;
    #pragma unroll
    for (int jt = 0; jt < 4; ++jt)
      #pragma unroll
      for (int r = 0; r < 4; ++r) s += st[jt][it][r];
    s += __shfl_xor(s, 16);
    s += __shfl_xor(s, 32);
    float inv = 1.0f / s;
    #pragma unroll
    for (int jt = 0; jt < 4; ++jt)
      #pragma unroll
      for (int r = 0; r < 4; ++r)
        pf[jt][it][r] = (_Float16)(st[jt][it][r] * inv);
  }

  // ---- qkv pass 2: V (token-major) — after softmax so vf isn't live long ----
  f32x4 av[4][2];
  #pragma unroll
  for (int a = 0; a < 4; ++a) { av[a][0] = Z4; av[a][1] = Z4; }
  #pragma unroll 2
  for (int kk = 0; kk < 8; ++kk) {
    uint4 wb0 = wsrc[kk*384 + 4*64];
    uint4 wb1 = wsrc[kk*384 + 5*64];
    bf16x8 xf[4];
    #pragma unroll
    for (int tt = 0; tt < 4; ++tt)
      xf[tt] = *(const bf16x8*)(smem + (tt*16 + ll)*512 + ((kk*64 + lg*16) ^ xsw));
    bf16x8 wv0 = *(const bf16x8*)&wb0, wv1 = *(const bf16x8*)&wb1;
    #pragma unroll
    for (int tt = 0; tt < 4; ++tt) {
      av[tt][0] = MFMA32(xf[tt], wv0, av[tt][0]);
      av[tt][1] = MFMA32(xf[tt], wv1, av[tt][1]);
    }
  }
  half4 vf[2][4];
  {
    float bv0 = qkvb[512 + w*32 + ll];
    float bv1 = qkvb[512 + w*32 + 16 + ll];
    #pragma unroll
    for (int tt = 0; tt < 4; ++tt)
      #pragma unroll
      for (int e = 0; e < 4; ++e) {
        vf[0][tt][e] = (_Float16)(av[tt][0][e] + bv0);
        vf[1][tt][e] = (_Float16)(av[tt][1][e] + bv1);
      }
  }

  // ---- PV: O^T = V^T * P. acc: col=token i, row=d within 16-tile ----
  f32x4 ot[2][4];
  #pragma unroll
  for (int a = 0; a < 2; ++a)
    #pragma unroll
    for (int b = 0; b < 4; ++b) ot[a][b] = Z4;
  #pragma unroll
  for (int dt = 0; dt < 2; ++dt)
    #pragma unroll
    for (int it = 0; it < 4; ++it)
      #pragma unroll
      for (int jt = 0; jt < 4; ++jt)
        ot[dt][it] = MFMA16H(vf[dt][jt], pf[jt][it], ot[dt][it]);

  __syncthreads();   // all x reads done -> smem reusable as O

  // ---- write O [i][c] bf16 (swz (i&7)<<4); P was pre-normalized ----
  #pragma unroll
  for (int it = 0; it < 4; ++it) {
    int i = it*16 + ll;
    int isw = (i & 7) << 4;
    #pragma unroll
    for (int dt = 0; dt < 2; ++dt) {
      int c0 = w*32 + dt*16 + lg*4;
      uint2 u;
      u.x = pk2(ot[dt][it][0], ot[dt][it][1]);
      u.y = pk2(ot[dt][it][2], ot[dt][it][3]);
      *(uint2*)(smem + i*512 + ((c0*2) ^ isw)) = u;
    }
  }
  __syncthreads();

  // ---- proj GEMM: out = O @ proj_w^T + proj_b; wave w -> cols [32w,32w+32) ----
  f32x4 ap[4][2];
  #pragma unroll
  for (int a = 0; a < 4; ++a) { ap[a][0] = Z4; ap[a][1] = Z4; }
  const uint4* psrc = (const uint4*)wproj + l;     // + (kk*16+fb)*64
  uint4 pbuf[2];
  pbuf[0] = psrc[(2*w)*64];
  pbuf[1] = psrc[(2*w + 1)*64];
  #pragma unroll 2
  for (int kk = 0; kk < 8; ++kk) {
    bf16x8 bfr0 = *(const bf16x8*)&pbuf[0];
    bf16x8 bfr1 = *(const bf16x8*)&pbuf[1];
    if (kk < 7) {
      pbuf[0] = psrc[((kk+1)*16 + 2*w)*64];
      pbuf[1] = psrc[((kk+1)*16 + 2*w + 1)*64];
    }
    bf16x8 af[4];
    #pragma unroll
    for (int mt = 0; mt < 4; ++mt) {
      int i = mt*16 + ll;
      af[mt] = *(const bf16x8*)(smem + ((i*512 + kk*64 + lg*16) ^ ((i & 7) << 4)));
    }
    #pragma unroll
    for (int mt = 0; mt < 4; ++mt) {
      ap[mt][0] = MFMA32(af[mt], bfr0, ap[mt][0]);
      ap[mt][1] = MFMA32(af[mt], bfr1, ap[mt][1]);
    }
  }

  float pb0 = projb[w*32 + ll], pb1 = projb[w*32 + 16 + ll];
  float* op = out + (size_t)blk*WN*CD;
  #pragma unroll
  for (int mt = 0; mt < 4; ++mt)
    #pragma unroll
    for (int r = 0; r < 4; ++r) {
      int i = mt*16 + lg*4 + r;
      if (i < WN) {
        op[i*CD + w*32 + ll]      = ap[mt][0][r] + pb0;
        op[i*CD + w*32 + 16 + ll] = ap[mt][1][r] + pb1;
      }
    }
}

extern "C" void kernel_launch(void* const* d_in, const int* in_sizes, int n_in,
                              void* d_out, int out_size, void* d_ws, size_t ws_size,
                              hipStream_t stream) {
  const float* x      = (const float*)d_in[0];
  const float* mask   = (const float*)d_in[1];
  const float* qkv_w  = (const float*)d_in[2];
  const float* qkv_b  = (const float*)d_in[3];
  const float* proj_w = (const float*)d_in[4];
  const float* proj_b = (const float*)d_in[5];
  const float* rpb    = (const float*)d_in[6];
  const int*   relidx = (const int*)d_in[7];

  char* ws = (char*)d_ws;
  unsigned short* wqkv  = (unsigned short*)(ws + WS_WQKV);
  unsigned short* wproj = (unsigned short*)(ws + WS_WPROJ);
  unsigned short* tblw  = (unsigned short*)(ws + WS_TBL);
  float* out = (float*)d_out;

  prep_kernel<<<8192, 256, 0, stream>>>(qkv_w, proj_w, rpb, relidx, mask,
                                        wqkv, wproj, tblw);
  wattn_fused<<<4096, 512, 0, stream>>>(x, qkv_b, proj_b, wqkv, wproj,
                                        tblw, out);
}

// Round 5
// 232.541 us; speedup vs baseline: 1.3850x; 1.0586x over previous
//
#include <hip/hip_runtime.h>
#include <stdint.h>

// Fused Swin window-attention, MI355X gfx950.  v4b: f16 internals +
// all bias/mask/scale adds folded into MFMA C-operand initializers.
// One workgroup (512 thr = 8 waves) per window; wave w = head w.
// Phase order: stage x -> QK^T proj (acc init = qkv bias) -> S (acc init =
// (bias+mask)*log2e table) -> exp2+normalize -> P frags -> V proj -> PV ->
// O to LDS (+v-bias, valid since softmax rows sum to 1) -> proj GEMM
// (acc init = proj bias).

#define WN 49      // tokens per window
#define CD 256     // channels
#define NH 8       // heads

typedef float    f32x4  __attribute__((ext_vector_type(4)));
typedef _Float16 half8  __attribute__((ext_vector_type(8)));
typedef _Float16 half4  __attribute__((ext_vector_type(4)));
typedef __fp16   fp16x2 __attribute__((ext_vector_type(2)));

#define MFMA32H(a,b,c) __builtin_amdgcn_mfma_f32_16x16x32_f16((a),(b),(c),0,0,0)
#define MFMA16H(a,b,c) __builtin_amdgcn_mfma_f32_16x16x16f16((a),(b),(c),0,0,0)

__device__ __forceinline__ unsigned pkh(float a, float b) {
  fp16x2 h = __builtin_amdgcn_cvt_pkrtz(a, b);
  union { fp16x2 h; unsigned u; } c; c.h = h; return c.u;
}
__device__ __forceinline__ half4 cvt4(f32x4 v) {
  union { unsigned u[2]; half4 h; } c;
  c.u[0] = pkh(v[0], v[1]);
  c.u[1] = pkh(v[2], v[3]);
  return c.h;
}

// ---------------- workspace layout (bytes) ----------------
// WQKV : [8 h][8 kk][6 fb][64 lane][8 f16]  fragment-major qkv_w,
//        K-fragments (fb 2,3) pre-scaled by hd^-0.5*log2e        = 393216
// WPROJ: [8 kk][16 fb][64 lane][8 f16]      fragment-major proj_w = 131072
// TBL  : [64 mw][8 h][4 it][4 jt][64 lane] float4 = S-acc C-init
//        (bias+mask)*log2e, j>=49 -> -21640                       = 8388608
#define WS_WQKV  0
#define WS_WPROJ 393216
#define WS_TBL   524288

__global__ __launch_bounds__(256) void prep_kernel(
    const float* __restrict__ qkv_w, const float* __restrict__ proj_w,
    const float* __restrict__ rpb,   const int*   __restrict__ relidx,
    const float* __restrict__ mask,
    _Float16* __restrict__ wqkv, _Float16* __restrict__ wproj,
    float* __restrict__ tblw)
{
  const float kscale = 0.17677669529663687f * 1.4426950408889634f;
  int t = blockIdx.x * blockDim.x + threadIdx.x;
  if (t < 8*8*6*64) {                      // qkv_w fragments, head-grouped rows
    int l    = t & 63;
    int fb   = (t >> 6) % 6;
    int rest = t / (64*6);
    int kk = rest & 7, h = rest >> 3;
    int rbase = (fb < 2) ? (h*32 + fb*16)
              : (fb < 4) ? (256 + h*32 + (fb-2)*16)
                         : (512 + h*32 + (fb-4)*16);
    float sc = (fb == 2 || fb == 3) ? kscale : 1.0f;
    int row = rbase + (l & 15);
    int col = kk*32 + (l >> 4)*8;
    const float* src = qkv_w + row*CD + col;
    _Float16* dst = wqkv + (size_t)t*8;
    #pragma unroll
    for (int j2 = 0; j2 < 8; ++j2) dst[j2] = (_Float16)(src[j2] * sc);
  }
  if (t < 8*16*64) {                       // proj_w fragments
    int l  = t & 63;
    int fb = (t >> 6) & 15;
    int kk = t >> 10;
    int row = fb*16 + (l & 15);
    int col = kk*32 + (l >> 4)*8;
    const float* src = proj_w + row*CD + col;
    _Float16* dst = wproj + (size_t)t*8;
    #pragma unroll
    for (int j2 = 0; j2 < 8; ++j2) dst[j2] = (_Float16)src[j2];
  }
  if (t < 64*8*4*4*64) {                   // S-acc C-init table, frag-major
    int l  = t & 63;
    int jt = (t >> 6) & 3;
    int it = (t >> 8) & 3;
    int h  = (t >> 10) & 7;
    int mw = t >> 13;
    int i  = it*16 + (l & 15);
    int ii = i < WN ? i : WN - 1;          // padded query cols: copy row 48
    float4 v;
    #pragma unroll
    for (int e = 0; e < 4; ++e) {
      int j = jt*16 + (l >> 4)*4 + e;
      float val = -21640.0f;               // padded keys: exp2 -> 0
      if (j < WN)
        val = (rpb[relidx[ii*WN + j]*NH + h] + mask[mw*WN*WN + ii*WN + j])
              * 1.4426950408889634f;
      ((float*)&v)[e] = val;
    }
    ((float4*)tblw)[t] = v;
  }
}

// LDS: 32 KB. Phase 1: x f16 [64 tok][256 ch], byte-swizzle ^((row&7)<<4).
//              Phase 2 (after barrier): O f16 [64 tok][256 ch], same swizzle.
__global__ __launch_bounds__(512, 4) void wattn_fused(
    const float* __restrict__ x,
    const float* __restrict__ qkvb,
    const float* __restrict__ projb,
    const _Float16* __restrict__ wqkv,
    const _Float16* __restrict__ wproj,
    const float* __restrict__ tbl,
    float* __restrict__ out)
{
  __shared__ char smem[32768] __attribute__((aligned(16)));
  const int tid = threadIdx.x;
  const int w  = tid >> 6;     // wave = head
  const int l  = tid & 63;
  const int lg = l >> 4;
  const int ll = l & 15;
  const int blk = blockIdx.x;
  const int xsw = (ll & 7) << 4;
  const f32x4 Z4 = {0.f, 0.f, 0.f, 0.f};

  // ---- stage x (fp32 -> f16, swizzled), rows 49..63 zeroed ----
  {
    int row = tid >> 3, seg = tid & 7;
    char* dst = smem + row*512;
    int cb = seg*64;
    int sw = (row & 7) << 4;
    if (row < WN) {
      const float4* s4 = (const float4*)(x + (size_t)blk*WN*CD + row*CD + seg*32);
      #pragma unroll
      for (int q = 0; q < 4; ++q) {
        float4 a = s4[2*q], b = s4[2*q+1];
        uint4 u;
        u.x = pkh(a.x, a.y); u.y = pkh(a.z, a.w);
        u.z = pkh(b.x, b.y); u.w = pkh(b.z, b.w);
        *(uint4*)(dst + ((cb + q*16) ^ sw)) = u;
      }
    } else {
      uint4 z = {0u,0u,0u,0u};
      #pragma unroll
      for (int q = 0; q < 4; ++q) *(uint4*)(dst + ((cb + q*16) ^ sw)) = z;
    }
  }
  __syncthreads();

  const uint4* wsrc = (const uint4*)wqkv + (size_t)(w*8)*384 + l;  // +kk*384+fb*64

  // ---- qkv pass 1: Q^T, K^T (channel-major); acc init = bias ----
  // acc: col(lane&15)=token, row((lane>>4)*4+r)=out-channel within 16-tile.
  const float kscale = 0.17677669529663687f * 1.4426950408889634f;
  f32x4 aq[2][4], ak[2][4];
  #pragma unroll
  for (int ds = 0; ds < 2; ++ds) {
    f32x4 bq = *(const f32x4*)(qkvb + w*32 + ds*16 + lg*4);
    f32x4 bk = *(const f32x4*)(qkvb + 256 + w*32 + ds*16 + lg*4);
    #pragma unroll
    for (int e = 0; e < 4; ++e) bk[e] *= kscale;
    #pragma unroll
    for (int tt = 0; tt < 4; ++tt) { aq[ds][tt] = bq; ak[ds][tt] = bk; }
  }

  #pragma unroll 2
  for (int kk = 0; kk < 8; ++kk) {
    uint4 wb[4];
    #pragma unroll
    for (int fb = 0; fb < 4; ++fb) wb[fb] = wsrc[kk*384 + fb*64];
    half8 xf[4];
    #pragma unroll
    for (int tt = 0; tt < 4; ++tt)
      xf[tt] = *(const half8*)(smem + (tt*16 + ll)*512 + ((kk*64 + lg*16) ^ xsw));
    half8 wq0 = *(const half8*)&wb[0], wq1 = *(const half8*)&wb[1];
    half8 wk0 = *(const half8*)&wb[2], wk1 = *(const half8*)&wb[3];
    #pragma unroll
    for (int tt = 0; tt < 4; ++tt) {
      aq[0][tt] = MFMA32H(wq0, xf[tt], aq[0][tt]);
      aq[1][tt] = MFMA32H(wq1, xf[tt], aq[1][tt]);
      ak[0][tt] = MFMA32H(wk0, xf[tt], ak[0][tt]);
      ak[1][tt] = MFMA32H(wk1, xf[tt], ak[1][tt]);
    }
  }

  // cvt to f16 frags (bias/scale already inside acc)
  half4 qf[2][4], kf[2][4];
  #pragma unroll
  for (int ds = 0; ds < 2; ++ds)
    #pragma unroll
    for (int tt = 0; tt < 4; ++tt) {
      qf[ds][tt] = cvt4(aq[ds][tt]);
      kf[ds][tt] = cvt4(ak[ds][tt]);
    }

  // ---- S^T = K * Q^T (64x64); acc init = (bias+mask)*log2e table ----
  f32x4 st[4][4];
  {
    const f32x4* tb = (const f32x4*)tbl + ((size_t)((blk & 63)*8 + w) << 10) + l;
    #pragma unroll
    for (int it = 0; it < 4; ++it)
      #pragma unroll
      for (int jt = 0; jt < 4; ++jt)
        st[jt][it] = tb[(it*4 + jt)*64];
  }
  #pragma unroll
  for (int jt = 0; jt < 4; ++jt)
    #pragma unroll
    for (int it = 0; it < 4; ++it) {
      st[jt][it] = MFMA16H(kf[0][jt], qf[0][it], st[jt][it]);
      st[jt][it] = MFMA16H(kf[1][jt], qf[1][it], st[jt][it]);
    }

  // ---- softmax: p = exp2(st) (table pre-scaled by log2e; no max-sub) ----
  #pragma unroll
  for (int jt = 0; jt < 4; ++jt)
    #pragma unroll
    for (int it = 0; it < 4; ++it)
      #pragma unroll
      for (int r = 0; r < 4; ++r)
        st[jt][it][r] = __builtin_amdgcn_exp2f(st[jt][it][r]);

  // ---- row sums + normalize + cvt -> P frags (PV B-operand) ----
  half4 pf[4][4];
  #pragma unroll
  for (int it = 0; it < 4; ++it) {
    float s = 0.f;
    #pragma unroll
    for (int jt = 0; jt < 4; ++jt)
      #pragma unroll
      for (int r = 0; r < 4; ++r) s += st[jt][it][r];
    s += __shfl_xor(s, 16);
    s += __shfl_xor(s, 32);
    float inv = 1.0f / s;
    #pragma unroll
    for (int jt = 0; jt < 4; ++jt) {
      f32x4 p;
      #pragma unroll
      for (int r = 0; r < 4; ++r) p[r] = st[jt][it][r] * inv;
      pf[jt][it] = cvt4(p);
    }
  }

  // ---- qkv pass 2: V (token-major), acc init 0 (v-bias folded into O) ----
  f32x4 av[4][2];
  #pragma unroll
  for (int a = 0; a < 4; ++a) { av[a][0] = Z4; av[a][1] = Z4; }
  #pragma unroll 2
  for (int kk = 0; kk < 8; ++kk) {
    uint4 wb0 = wsrc[kk*384 + 4*64];
    uint4 wb1 = wsrc[kk*384 + 5*64];
    half8 xf[4];
    #pragma unroll
    for (int tt = 0; tt < 4; ++tt)
      xf[tt] = *(const half8*)(smem + (tt*16 + ll)*512 + ((kk*64 + lg*16) ^ xsw));
    half8 wv0 = *(const half8*)&wb0, wv1 = *(const half8*)&wb1;
    #pragma unroll
    for (int tt = 0; tt < 4; ++tt) {
      av[tt][0] = MFMA32H(xf[tt], wv0, av[tt][0]);
      av[tt][1] = MFMA32H(xf[tt], wv1, av[tt][1]);
    }
  }
  half4 vf[2][4];
  #pragma unroll
  for (int tt = 0; tt < 4; ++tt) {
    vf[0][tt] = cvt4(av[tt][0]);
    vf[1][tt] = cvt4(av[tt][1]);
  }

  // ---- PV: O^T = V^T * P. acc: col=token i, row=d within 16-tile ----
  f32x4 ot[2][4];
  #pragma unroll
  for (int a = 0; a < 2; ++a)
    #pragma unroll
    for (int b = 0; b < 4; ++b) ot[a][b] = Z4;
  #pragma unroll
  for (int dt = 0; dt < 2; ++dt)
    #pragma unroll
    for (int it = 0; it < 4; ++it)
      #pragma unroll
      for (int jt = 0; jt < 4; ++jt)
        ot[dt][it] = MFMA16H(vf[dt][jt], pf[jt][it], ot[dt][it]);

  __syncthreads();   // all x reads done -> smem reusable as O

  // ---- write O [i][c] f16 (swz (i&7)<<4), + v-bias (rows of P sum to 1) ----
  {
    f32x4 bv[2];
    #pragma unroll
    for (int dt = 0; dt < 2; ++dt)
      bv[dt] = *(const f32x4*)(qkvb + 512 + w*32 + dt*16 + lg*4);
    #pragma unroll
    for (int it = 0; it < 4; ++it) {
      int i = it*16 + ll;
      int isw = (i & 7) << 4;
      #pragma unroll
      for (int dt = 0; dt < 2; ++dt) {
        int c0 = w*32 + dt*16 + lg*4;
        uint2 u;
        u.x = pkh(ot[dt][it][0] + bv[dt][0], ot[dt][it][1] + bv[dt][1]);
        u.y = pkh(ot[dt][it][2] + bv[dt][2], ot[dt][it][3] + bv[dt][3]);
        *(uint2*)(smem + i*512 + ((c0*2) ^ isw)) = u;
      }
    }
  }
  __syncthreads();

  // ---- proj GEMM: out = O @ proj_w^T; acc init = proj bias ----
  f32x4 ap[4][2];
  {
    float pb0 = projb[w*32 + ll], pb1 = projb[w*32 + 16 + ll];
    f32x4 i0 = {pb0, pb0, pb0, pb0};
    f32x4 i1 = {pb1, pb1, pb1, pb1};
    #pragma unroll
    for (int a = 0; a < 4; ++a) { ap[a][0] = i0; ap[a][1] = i1; }
  }
  const uint4* psrc = (const uint4*)wproj + l;     // + (kk*16+fb)*64
  uint4 pbuf[2];
  pbuf[0] = psrc[(2*w)*64];
  pbuf[1] = psrc[(2*w + 1)*64];
  #pragma unroll 2
  for (int kk = 0; kk < 8; ++kk) {
    half8 bfr0 = *(const half8*)&pbuf[0];
    half8 bfr1 = *(const half8*)&pbuf[1];
    if (kk < 7) {
      pbuf[0] = psrc[((kk+1)*16 + 2*w)*64];
      pbuf[1] = psrc[((kk+1)*16 + 2*w + 1)*64];
    }
    half8 af[4];
    #pragma unroll
    for (int mt = 0; mt < 4; ++mt) {
      int i = mt*16 + ll;
      af[mt] = *(const half8*)(smem + ((i*512 + kk*64 + lg*16) ^ ((i & 7) << 4)));
    }
    #pragma unroll
    for (int mt = 0; mt < 4; ++mt) {
      ap[mt][0] = MFMA32H(af[mt], bfr0, ap[mt][0]);
      ap[mt][1] = MFMA32H(af[mt], bfr1, ap[mt][1]);
    }
  }

  float* op = out + (size_t)blk*WN*CD;
  #pragma unroll
  for (int mt = 0; mt < 4; ++mt)
    #pragma unroll
    for (int r = 0; r < 4; ++r) {
      int i = mt*16 + lg*4 + r;
      if (i < WN) {
        op[i*CD + w*32 + ll]      = ap[mt][0][r];
        op[i*CD + w*32 + 16 + ll] = ap[mt][1][r];
      }
    }
}

extern "C" void kernel_launch(void* const* d_in, const int* in_sizes, int n_in,
                              void* d_out, int out_size, void* d_ws, size_t ws_size,
                              hipStream_t stream) {
  const float* x      = (const float*)d_in[0];
  const float* mask   = (const float*)d_in[1];
  const float* qkv_w  = (const float*)d_in[2];
  const float* qkv_b  = (const float*)d_in[3];
  const float* proj_w = (const float*)d_in[4];
  const float* proj_b = (const float*)d_in[5];
  const float* rpb    = (const float*)d_in[6];
  const int*   relidx = (const int*)d_in[7];

  char* ws = (char*)d_ws;
  _Float16* wqkv  = (_Float16*)(ws + WS_WQKV);
  _Float16* wproj = (_Float16*)(ws + WS_WPROJ);
  float*    tblw  = (float*)(ws + WS_TBL);
  float* out = (float*)d_out;

  prep_kernel<<<2048, 256, 0, stream>>>(qkv_w, proj_w, rpb, relidx, mask,
                                        wqkv, wproj, tblw);
  wattn_fused<<<4096, 512, 0, stream>>>(x, qkv_b, proj_b, wqkv, wproj,
                                        tblw, out);
}